// Round 1
// 408.092 us; speedup vs baseline: 1.0227x; 1.0227x over previous
//
#include <hip/hip_runtime.h>
#include <hip/hip_bf16.h>

typedef unsigned short u16;
typedef unsigned int   u32;
typedef unsigned long long u64;

typedef __attribute__((ext_vector_type(8))) short  short8;   // 8 x bf16 (4 VGPRs)
typedef __attribute__((ext_vector_type(4))) float  floatx4;  // MFMA C/D

// fixed-point packing for the u64 atomic scatter:
//   each edge adds (BIAS + round(z * SCALE)) into each 32-bit half.
//   BIAS=2^26 keeps halves positive (no carry across the 64-bit midpoint);
//   cnt recovered as (lo + 2^25) >> 26 since |sum fix| << 2^25.
#define FIX_SCALE 65536.0f
#define FIX_INV   (1.0f / 65536.0f)
#define FIX_BIAS  (1 << 26)

// round-to-nearest-even pack of two f32 into packed bf16x2 (lo = low u16)
__device__ __forceinline__ u32 rne_pack(float lo, float hi) {
  u32 bl = __float_as_uint(lo), bh = __float_as_uint(hi);
  u32 rl = ((bl + 0x7FFFu + ((bl >> 16) & 1u)) >> 16) & 0xFFFFu;
  u32 rh = (bh + 0x7FFFu + ((bh >> 16) & 1u)) & 0xFFFF0000u;
  return rl | rh;
}

// scale a packed-bf16 x8 msg fragment by w (f32), truncate back to bf16
__device__ __forceinline__ short8 scale_frag(uint4 mraw, float w) {
  const u32* in = (const u32*)&mraw;
  uint4 o; u32* ou = (u32*)&o;
  #pragma unroll
  for (int i = 0; i < 4; ++i) {
    float lo = __uint_as_float(in[i] << 16) * w;
    float hi = __uint_as_float(in[i]) * w;   // low-mantissa noise << bf16 ulp
    ou[i] = __builtin_amdgcn_perm(__float_as_uint(hi), __float_as_uint(lo), 0x07060302u);
  }
  return *(short8*)&o;
}

// ---------------------------------------------------------------------------
// fused: per 256-edge block:
//   A) cluster distances via MFMA (f32 loads -> bf16 frags), student-t ->
//      head-normalize -> mean -> softmax  => w[e][8] in LDS
//   B) z[e] = (w (x) msg) @ W via K=512 MFMA GEMM (W converted+swizzled to
//      LDS per block).  W-columns are PERMUTED across B-fragment slots so
//      that acc[s][0/1][i] hold adjacent output cols (2*ln, 2*ln+1) and
//      acc[s][2/3][i] hold (2*ln+32, 2*ln+33)  =>  epilogue packs each col
//      pair into ONE u64 fixed-point atomic (2x fewer atomic ops, same bytes).
// ---------------------------------------------------------------------------
__global__ __launch_bounds__(256, 2) void fused_kernel(
    const float* __restrict__ msg, const float* __restrict__ xj,
    const float* __restrict__ eij, const float* __restrict__ kc,
    const float* __restrict__ Wg, const int* __restrict__ idx,
    u64* __restrict__ o64, int E) {
  __shared__ __align__(16) char un[65536];
  float* tl = (float*)un;            // phase A: 256*33 f32 (col 32 = ||x||^2)
  u16*   Wl = (u16*)un;              // phase B: 32768 bf16 = 64 KB swizzled W
  __shared__ __align__(16) float wsm[2048];   // w[256][8]
  __shared__ float kn[32];

  const int tid  = threadIdx.x;
  const int lane = tid & 63, wv = tid >> 6;
  const int ln   = lane & 15, q  = lane >> 4;
  const int e0   = blockIdx.x * 256;

  // ---- A-frags (cluster centers 32x64, f32 -> bf16) + ||k_c||^2 ----
  const float4* kc4 = (const float4*)kc;
  short8 af[2][2];
  float knp[2] = {0.f, 0.f};
  #pragma unroll
  for (int mt = 0; mt < 2; ++mt) {
    #pragma unroll
    for (int kk = 0; kk < 2; ++kk) {
      size_t b4 = (size_t)(mt * 16 + ln) * 16 + kk * 8 + q * 2;
      float4 c0 = kc4[b4], c1 = kc4[b4 + 1];
      knp[mt] += c0.x*c0.x + c0.y*c0.y + c0.z*c0.z + c0.w*c0.w
               + c1.x*c1.x + c1.y*c1.y + c1.z*c1.z + c1.w*c1.w;
      u32 pk[4] = { rne_pack(c0.x, c0.y), rne_pack(c0.z, c0.w),
                    rne_pack(c1.x, c1.y), rne_pack(c1.z, c1.w) };
      af[mt][kk] = *(short8*)pk;
    }
    float s = knp[mt];
    s += __shfl_xor(s, 16);
    s += __shfl_xor(s, 32);
    if (wv == 0 && q == 0) kn[mt * 16 + ln] = s;
  }

  // ---- phase A: dot[c][e] via MFMA; B-frags built from f32 global ----
  const float4* xj4  = (const float4*)xj;
  const float4* eij4 = (const float4*)eij;
  #pragma unroll
  for (int g = 0; g < 4; ++g) {
    int el = wv * 64 + g * 16 + ln;
    int ge = e0 + el; if (ge >= E) ge = 0;   // clamp: finite data, discarded
    size_t b4 = (size_t)ge * 16 + q * 2;
    float4 x0 = xj4[b4],     x1 = xj4[b4 + 1];
    float4 x2 = xj4[b4 + 8], x3 = xj4[b4 + 9];
    float4 ea0 = eij4[b4],     ea1 = eij4[b4 + 1];
    float4 ea2 = eij4[b4 + 8], ea3 = eij4[b4 + 9];
    float s0x = x0.x+ea0.x, s0y = x0.y+ea0.y, s0z = x0.z+ea0.z, s0w = x0.w+ea0.w;
    float s1x = x1.x+ea1.x, s1y = x1.y+ea1.y, s1z = x1.z+ea1.z, s1w = x1.w+ea1.w;
    float s2x = x2.x+ea2.x, s2y = x2.y+ea2.y, s2z = x2.z+ea2.z, s2w = x2.w+ea2.w;
    float s3x = x3.x+ea3.x, s3y = x3.y+ea3.y, s3z = x3.z+ea3.z, s3w = x3.w+ea3.w;
    float ps = s0x*s0x + s0y*s0y + s0z*s0z + s0w*s0w
             + s1x*s1x + s1y*s1y + s1z*s1z + s1w*s1w
             + s2x*s2x + s2y*s2y + s2z*s2z + s2w*s2w
             + s3x*s3x + s3y*s3y + s3z*s3z + s3w*s3w;
    u32 p0[4] = { rne_pack(s0x, s0y), rne_pack(s0z, s0w),
                  rne_pack(s1x, s1y), rne_pack(s1z, s1w) };
    u32 p1[4] = { rne_pack(s2x, s2y), rne_pack(s2z, s2w),
                  rne_pack(s3x, s3y), rne_pack(s3z, s3w) };
    ps += __shfl_xor(ps, 16);   // sum over the 4 k-chunks (q lanes)
    ps += __shfl_xor(ps, 32);
    short8 bb0 = *(short8*)p0, bb1 = *(short8*)p1;
    floatx4 acc0 = {0.f,0.f,0.f,0.f}, acc1 = {0.f,0.f,0.f,0.f};
    acc0 = __builtin_amdgcn_mfma_f32_16x16x32_bf16(af[0][0], bb0, acc0, 0, 0, 0);
    acc0 = __builtin_amdgcn_mfma_f32_16x16x32_bf16(af[0][1], bb1, acc0, 0, 0, 0);
    acc1 = __builtin_amdgcn_mfma_f32_16x16x32_bf16(af[1][0], bb0, acc1, 0, 0, 0);
    acc1 = __builtin_amdgcn_mfma_f32_16x16x32_bf16(af[1][1], bb1, acc1, 0, 0, 0);
    // D: col(edge)=lane&15, row(center)=q*4+i
    #pragma unroll
    for (int i = 0; i < 4; ++i) {
      tl[el * 33 + (q * 4 + i)]      = acc0[i];
      tl[el * 33 + 16 + (q * 4 + i)] = acc1[i];
    }
    if (q == 0) tl[el * 33 + 32] = ps;
  }
  __syncthreads();

  // ---- softmax per edge (one thread per edge) ----
  {
    int e = tid;
    bool valid = (e0 + e) < E;
    float xn = tl[e * 33 + 32];
    float tv[32];
    float hs[4] = {0.f, 0.f, 0.f, 0.f};
    #pragma unroll
    for (int c = 0; c < 32; ++c) {
      float dist = kn[c] + xn - 2.f * tl[e * 33 + c];
      dist = dist > 0.f ? dist : 0.f;
      float t = 1.f / (1.f + dist);          // gamma=1 -> (1+d)^-1
      tv[c] = t;
      hs[c >> 3] += t;
    }
    float r0 = 1.f / hs[0], r1 = 1.f / hs[1], r2 = 1.f / hs[2], r3 = 1.f / hs[3];
    float m[8], mx = -1e30f;
    #pragma unroll
    for (int k = 0; k < 8; ++k) {
      m[k] = 2.5f * (tv[k] * r0 + tv[8 + k] * r1 + tv[16 + k] * r2 + tv[24 + k] * r3);
      mx = m[k] > mx ? m[k] : mx;
    }
    float p[8], sum = 0.f;
    #pragma unroll
    for (int k = 0; k < 8; ++k) { p[k] = __expf(m[k] - mx); sum += p[k]; }
    float rs = valid ? (1.f / sum) : 0.f;    // invalid edges -> w = 0
    floatx4 w0 = {p[0]*rs, p[1]*rs, p[2]*rs, p[3]*rs};
    floatx4 w1 = {p[4]*rs, p[5]*rs, p[6]*rs, p[7]*rs};
    *(floatx4*)&wsm[e * 8]     = w0;
    *(floatx4*)&wsm[e * 8 + 4] = w1;
  }
  __syncthreads();   // all tl reads done before Wl overwrites the union

  // ---- phase B: stage W (f32 -> bf16, swizzled) into LDS ----
  // Column permutation: W col n lands in B-frag slot m(n) = t*16 + (n&31)/2,
  // t = (n&1) + 2*(n>=32), so that slot (t, ln) holds W col
  // {2*ln, 2*ln+1, 2*ln+32, 2*ln+33}[t].  m(n) is a bijection of the
  // per-wave store addresses -> identical LDS bank profile to the old layout;
  // K-loop read addresses are unchanged entirely.
  #pragma unroll
  for (int it = 0; it < 16; ++it) {
    int c  = (tid >> 6) + it * 4;            // 0..63 = (kk,q2)
    int kk = c >> 2, q2 = c & 3, n = tid & 63;
    const float* src = Wg + (size_t)(kk * 32 + q2 * 8) * 64 + n;
    u32 pk[4];
    #pragma unroll
    for (int jp = 0; jp < 4; ++jp)
      pk[jp] = rne_pack(src[(jp * 2) * 64], src[(jp * 2 + 1) * 64]);
    int tt = (n & 1) + ((n >> 5) << 1);
    int mm = tt * 16 + ((n & 31) >> 1);
    *(uint4*)&Wl[(c * 64 + mm) * 8] = *(uint4*)pk;
  }

  // msg fragments (f32 -> packed bf16) and w rows
  const float4* msg4 = (const float4*)msg;
  uint4 mf[4][2];
  const int edgebase = e0 + wv * 64;
  #pragma unroll
  for (int s = 0; s < 4; ++s) {
    int eg = edgebase + s * 16 + ln; if (eg >= E) eg = E - 1;
    size_t mb = (size_t)eg * 16 + q * 2;
    #pragma unroll
    for (int h = 0; h < 2; ++h) {
      float4 m0 = msg4[mb + h * 8], m1 = msg4[mb + h * 8 + 1];
      u32 pk[4] = { rne_pack(m0.x, m0.y), rne_pack(m0.z, m0.w),
                    rne_pack(m1.x, m1.y), rne_pack(m1.z, m1.w) };
      mf[s][h] = *(uint4*)pk;
    }
  }
  floatx4 wf[4][2];
  #pragma unroll
  for (int s = 0; s < 4; ++s) {
    int eL = wv * 64 + s * 16 + ln;
    wf[s][0] = *(floatx4*)&wsm[eL * 8];
    wf[s][1] = *(floatx4*)&wsm[eL * 8 + 4];
  }
  floatx4 acc[4][4];
  #pragma unroll
  for (int s = 0; s < 4; ++s)
    #pragma unroll
    for (int t = 0; t < 4; ++t) { floatx4 z = {0.f,0.f,0.f,0.f}; acc[s][t] = z; }
  __syncthreads();

  // K-loop: 8 clusters x 2 half-rows of 32 — no barriers inside.
  // Read addresses identical to the pre-permutation kernel.
  #pragma unroll
  for (int kb = 0; kb < 8; ++kb) {
    float wsc[4];
    #pragma unroll
    for (int s = 0; s < 4; ++s) wsc[s] = wf[s][kb >> 2][kb & 3];
    #pragma unroll
    for (int hh = 0; hh < 2; ++hh) {
      int kk = kb * 2 + hh;
      short8 bfr[4];
      #pragma unroll
      for (int t = 0; t < 4; ++t)
        bfr[t] = *(short8*)&Wl[((kk * 4 + q) * 64 + t * 16 + ln) * 8];
      #pragma unroll
      for (int s = 0; s < 4; ++s) {
        short8 a = scale_frag(mf[s][hh], wsc[s]);
        #pragma unroll
        for (int t = 0; t < 4; ++t)
          acc[s][t] = __builtin_amdgcn_mfma_f32_16x16x32_bf16(a, bfr[t], acc[s][t], 0, 0, 0);
      }
    }
  }

  // ---- epilogue: packed u64 fixed-point atomic scatter ----
  // acc[s][0][i], acc[s][1][i] = cols (2*ln, 2*ln+1)  -> pair index ln
  // acc[s][2][i], acc[s][3][i] = cols (2*ln+32, +33)  -> pair index 16+ln
  // 2 u64 atomics per (s,i) per lane  (was 4 f32 atomics): half the op count,
  // identical payload bytes and line-level coalescing (4 lines / instr).
  #pragma unroll
  for (int s = 0; s < 4; ++s) {
    #pragma unroll
    for (int i = 0; i < 4; ++i) {
      int eg = edgebase + s * 16 + q * 4 + i;
      if (eg < E) {
        int node = idx[eg];
        u64* dst = o64 + (size_t)node * 32 + ln;
        u32 l0 = (u32)((int)rintf(acc[s][0][i] * FIX_SCALE) + FIX_BIAS);
        u32 h0 = (u32)((int)rintf(acc[s][1][i] * FIX_SCALE) + FIX_BIAS);
        u32 l1 = (u32)((int)rintf(acc[s][2][i] * FIX_SCALE) + FIX_BIAS);
        u32 h1 = (u32)((int)rintf(acc[s][3][i] * FIX_SCALE) + FIX_BIAS);
        atomicAdd(dst,      ((u64)h0 << 32) | l0);
        atomicAdd(dst + 16, ((u64)h1 << 32) | l1);
      }
    }
  }
}

// ---------------------------------------------------------------------------
// finish: decode fixed-point u64 accumulators IN PLACE (same buffer as out),
// add bias, leaky_relu.  Each thread owns one 32B slice (4 u64 -> 8 f32),
// so the in-place read->write has no cross-thread hazard.
// ---------------------------------------------------------------------------
__global__ __launch_bounds__(256) void finish_packed(
    u64* __restrict__ a64, const float* __restrict__ b, int ng) {
  int g = blockIdx.x * 256 + threadIdx.x;
  if (g >= ng) return;                       // ng = N*8
  int node = g >> 3, pg = g & 7;
  u64* ap = a64 + (size_t)node * 32 + pg * 4;
  ulonglong4 v = *(ulonglong4*)ap;
  u32 w[8] = { (u32)v.x, (u32)(v.x >> 32), (u32)v.y, (u32)(v.y >> 32),
               (u32)v.z, (u32)(v.z >> 32), (u32)v.w, (u32)(v.w >> 32) };
  // per-node edge count from the bias term (exact: |sum fix| << 2^25)
  u32 cnt = (w[0] + (1u << 25)) >> 26;
  u32 cb  = cnt << 26;
  int col0 = pg * 8;
  float r[8];
  #pragma unroll
  for (int c = 0; c < 8; ++c) {
    float z = (float)(int)(w[c] - cb) * FIX_INV + b[col0 + c];
    r[c] = z > 0.f ? z : 0.01f * z;
  }
  float* op = (float*)a64 + (size_t)node * 64 + col0;
  *(float4*)op       = make_float4(r[0], r[1], r[2], r[3]);
  *(float4*)(op + 4) = make_float4(r[4], r[5], r[6], r[7]);
}

// ---------------------------------------------------------------------------
extern "C" void kernel_launch(void* const* d_in, const int* in_sizes, int n_in,
                              void* d_out, int out_size, void* d_ws, size_t ws_size,
                              hipStream_t stream) {
  // inputs (all f32 except index/num_nodes): 0 msg, 1 x_i (unused), 2 x_j,
  // 3 e_ij, 4 index (i32), 5 num_nodes, 6 k[4][8][64], 7 W[512][64], 8 b[64]
  const float* msg = (const float*)d_in[0];
  const float* xj  = (const float*)d_in[2];
  const float* eij = (const float*)d_in[3];
  const int*   idx = (const int*)d_in[4];
  const float* kc  = (const float*)d_in[6];
  const float* Wg  = (const float*)d_in[7];
  const float* bg  = (const float*)d_in[8];

  int E    = in_sizes[0] / 64;
  int Nout = out_size;                       // num_nodes * 64
  float* out = (float*)d_out;

  // out doubles as the u64 fixed-point accumulator (N*32 u64 == N*64 f32)
  hipMemsetAsync(out, 0, (size_t)Nout * 4, stream);

  int blocks = (E + 255) / 256;
  fused_kernel<<<blocks, 256, 0, stream>>>(msg, xj, eij, kc, Wg, idx,
                                           (u64*)out, E);

  int ng = Nout / 8;                         // N*8 decode threads
  finish_packed<<<(ng + 255) / 256, 256, 0, stream>>>((u64*)out, bg, ng);
}